// Round 3
// baseline (215.963 us; speedup 1.0000x reference)
//
#include <hip/hip_runtime.h>
#include <hip/hip_bf16.h>
#include <cstdint>

#define DEVI static __device__ __forceinline__

typedef __attribute__((ext_vector_type(8))) short short8v;  // 8 bf16 (4 VGPRs)
typedef __attribute__((ext_vector_type(4))) float f32x4;

DEVI ushort f2bf(float f) {  // fp32 -> bf16, round-to-nearest-even
  union { float f; uint32_t u; } v; v.f = f;
  uint32_t r = v.u + 0x7FFFu + ((v.u >> 16) & 1u);
  return (ushort)(r >> 16);
}
DEVI float bf2f(ushort u) {
  union { uint32_t u; float f; } v; v.u = ((uint32_t)u) << 16; return v.f;
}

// ---------------- pack weights: stacked bf16 [320][256] + bias [320] ----------------
__global__ __launch_bounds__(64) void pack_w_kernel(
    const float* __restrict__ Wq, const float* __restrict__ bq,
    const float* __restrict__ Wk, const float* __restrict__ bk,
    const float* __restrict__ Wv, const float* __restrict__ bv,
    ushort* __restrict__ WS, float* __restrict__ BS)
{
  const int r = blockIdx.x;      // 0..319: 0-31 q, 32-63 k, 64-319 v
  const int lane = threadIdx.x;  // 0..63
  const float* src; float bsv;
  if (r < 32)      { src = Wq + r * 256;        bsv = bq[r]; }
  else if (r < 64) { src = Wk + (r - 32) * 256; bsv = bk[r - 32]; }
  else             { src = Wv + (r - 64) * 256; bsv = bv[r - 64]; }
  float4 v = *(const float4*)(src + lane * 4);
  ushort4 o; o.x = f2bf(v.x); o.y = f2bf(v.y); o.z = f2bf(v.z); o.w = f2bf(v.w);
  *(ushort4*)(WS + r * 256 + lane * 4) = o;
  if (lane == 0) BS[r] = bsv;
}

// ---------------- projection as MFMA GEMM ----------------
// grid (128 i-tiles of 32, 4 b), block 256 (4 waves).
__global__ __launch_bounds__(256, 2) void proj_gemm_kernel(
    const float* __restrict__ x, const ushort* __restrict__ WS,
    const float* __restrict__ BS,
    ushort* __restrict__ qT, ushort* __restrict__ kT, ushort* __restrict__ vO)
{
  __shared__ alignas(16) char XT[32 * 512];  // [i][c*2B], byte ^= (i&15)<<4

  const int t = threadIdx.x;
  const int lane = t & 63;
  const int w = __builtin_amdgcn_readfirstlane(t >> 6);
  const int g = lane >> 4, m16 = lane & 15;
  const int b = blockIdx.y;
  const int i0 = blockIdx.x * 32;
  const size_t xb = (size_t)b * 256 * 4096;

  {  // stage: thread t handles i = t&31, c-group (t>>5)*4, 8 k-passes
    const int i = t & 31, cg = t >> 5;
    float vals[8][4];
    #pragma unroll
    for (int k = 0; k < 8; ++k) {
      const int c0 = k * 32 + cg * 4;
      #pragma unroll
      for (int r = 0; r < 4; ++r)
        vals[k][r] = x[xb + (size_t)(c0 + r) * 4096 + i0 + i];
    }
    char* row = XT + i * 512;
    const uint32_t sw = (uint32_t)((i & 15) << 4);
    #pragma unroll
    for (int k = 0; k < 8; ++k) {
      const int c0 = k * 32 + cg * 4;
      uint2 pk;
      pk.x = (uint32_t)f2bf(vals[k][0]) | ((uint32_t)f2bf(vals[k][1]) << 16);
      pk.y = (uint32_t)f2bf(vals[k][2]) | ((uint32_t)f2bf(vals[k][3]) << 16);
      *(uint2*)(row + (((uint32_t)(c0 * 2)) ^ sw)) = pk;
    }
  }
  __syncthreads();

  // B-frags (also used as A for the v case): lane m16 <-> row i, k-slot g*8+j
  short8v xf[2][8];
  {
    const uint32_t sw = (uint32_t)(m16 << 4);
    #pragma unroll
    for (int isub = 0; isub < 2; ++isub) {
      const char* row = XT + (isub * 16 + m16) * 512;
      #pragma unroll
      for (int kt = 0; kt < 8; ++kt)
        xf[isub][kt] = *(const short8v*)(row + (((uint32_t)(kt * 64 + g * 16)) ^ sw));
    }
  }

  const size_t bN = (size_t)b * 4096;
  #pragma unroll
  for (int si = 0; si < 5; ++si) {
    const int s = w + si * 4;  // o-subtile 0..19
    f32x4 acc0 = {0.f, 0.f, 0.f, 0.f}, acc1 = {0.f, 0.f, 0.f, 0.f};
    if (s < 4) {
      #pragma unroll
      for (int kt = 0; kt < 8; ++kt) {
        short8v wf = *(const short8v*)(WS + (s * 16 + m16) * 256 + kt * 32 + g * 8);
        acc0 = __builtin_amdgcn_mfma_f32_16x16x32_bf16(wf, xf[0][kt], acc0, 0, 0, 0);
        acc1 = __builtin_amdgcn_mfma_f32_16x16x32_bf16(wf, xf[1][kt], acc1, 0, 0, 0);
      }
      // D: rows o = s*16+g*4+r, cols i = m16
      float4 bias = *(const float4*)(BS + s * 16 + g * 4);
      ushort* dst = (s < 2) ? qT : kT;
      const int col = (s & 1) * 16 + g * 4;
      #pragma unroll
      for (int isub = 0; isub < 2; ++isub) {
        f32x4 a = isub ? acc1 : acc0;
        uint2 pk;
        pk.x = (uint32_t)f2bf(a[0] + bias.x) | ((uint32_t)f2bf(a[1] + bias.y) << 16);
        pk.y = (uint32_t)f2bf(a[2] + bias.z) | ((uint32_t)f2bf(a[3] + bias.w) << 16);
        *(uint2*)(dst + (bN + i0 + isub * 16 + m16) * 32 + col) = pk;
      }
    } else {
      #pragma unroll
      for (int kt = 0; kt < 8; ++kt) {
        short8v wf = *(const short8v*)(WS + (s * 16 + m16) * 256 + kt * 32 + g * 8);
        acc0 = __builtin_amdgcn_mfma_f32_16x16x32_bf16(xf[0][kt], wf, acc0, 0, 0, 0);
        acc1 = __builtin_amdgcn_mfma_f32_16x16x32_bf16(xf[1][kt], wf, acc1, 0, 0, 0);
      }
      // D: rows i = isub*16+g*4+r, cols c = s*16+m16-64
      const int c = s * 16 + m16 - 64;
      const float bc = BS[s * 16 + m16];
      #pragma unroll
      for (int isub = 0; isub < 2; ++isub) {
        f32x4 a = isub ? acc1 : acc0;
        uint2 pk;
        pk.x = (uint32_t)f2bf(a[0] + bc) | ((uint32_t)f2bf(a[1] + bc) << 16);
        pk.y = (uint32_t)f2bf(a[2] + bc) | ((uint32_t)f2bf(a[3] + bc) << 16);
        *(uint2*)(vO + ((size_t)(b * 256 + c)) * 4096 + i0 + isub * 16 + g * 4) = pk;
      }
    }
  }
}

// ---------------- fused flash attention, kj-split-2 x c-split-2 ----------------
// grid 1024 linear. xcd = bid&7 -> (b = xcd>>1, kjh = xcd&1); idx = bid>>3:
// ch = idx&1, q-tile = idx>>1. Each XCD's working set: 1 V-half + K-half + Q
// (~1.4 MB, L2-resident). 4 blocks/CU -> 4 waves/SIMD to fill the latency chain.
// Each wave: softmax for its 16 qi rows (duplicated across ch, cheap) + PV for
// c-slice [ch*128 + w*32, +32). P exchanged via double-buffered swizzled LDS.
__global__ __launch_bounds__(256, 4) void attn_kernel(
    const ushort* __restrict__ qT, const ushort* __restrict__ kT,
    const ushort* __restrict__ vB,
    float* __restrict__ O0, ushort* __restrict__ O1,
    float* __restrict__ M, float* __restrict__ L)
{
  __shared__ alignas(16) ushort Plds[2][64 * 64];  // [buf][qi][kj], XOR-swizzled rows
  __shared__ alignas(16) float Slds[2][64];        // per-row rescale factor

  const int lane = threadIdx.x & 63;
  const int w = __builtin_amdgcn_readfirstlane(threadIdx.x >> 6);
  const int g = lane >> 4, m16 = lane & 15;
  const int bid = blockIdx.x;
  const int xcd = bid & 7;
  const int b = xcd >> 1, kjh = xcd & 1;
  const int idx = bid >> 3;
  const int ch = idx & 1;
  const int q0 = (idx >> 1) * 64;
  const int kt0 = kjh * 32;
  const int cb = ch * 128 + w * 32;
  const float L2E = 1.44269504f;
  const size_t bN = (size_t)b * 4096;

  short8v qf = *(const short8v*)(qT + (bN + q0 + w * 16 + m16) * 32 + g * 8);

  f32x4 acc[4][2];
  f32x4 zz = {0.f, 0.f, 0.f, 0.f};
  #pragma unroll
  for (int t = 0; t < 4; ++t)
    #pragma unroll
    for (int ct = 0; ct < 2; ++ct) acc[t][ct] = zz;

  float mrun = -3.0e38f, lsum = 0.f;

  short8v kfA[4], kfB[4];
  #pragma unroll
  for (int j = 0; j < 4; ++j)
    kfA[j] = *(const short8v*)(kT + (bN + kt0 * 64 + j * 16 + m16) * 32 + g * 8);

  auto body = [&](int kt, short8v (&kfc)[4], short8v (&kfn)[4]) {
    const int kb = kt * 64, buf = kt & 1;
    const int knb = (kt < kt0 + 31) ? kb + 64 : kb;
    #pragma unroll
    for (int j = 0; j < 4; ++j)
      kfn[j] = *(const short8v*)(kT + (bN + knb + j * 16 + m16) * 32 + g * 8);
    short8v vf[2][2];
    #pragma unroll
    for (int ct = 0; ct < 2; ++ct)
      #pragma unroll
      for (int h = 0; h < 2; ++h)
        vf[ct][h] = *(const short8v*)(vB + ((size_t)(b * 256 + cb + ct * 16 + m16)) * 4096
                                      + kb + h * 32 + g * 8);
    float s[16];
    #pragma unroll
    for (int j = 0; j < 4; ++j) {
      f32x4 z = {0.f, 0.f, 0.f, 0.f};
      f32x4 s4 = __builtin_amdgcn_mfma_f32_16x16x32_bf16(kfc[j], qf, z, 0, 0, 0);
      s[j*4+0] = s4[0]; s[j*4+1] = s4[1]; s[j*4+2] = s4[2]; s[j*4+3] = s4[3];
    }
    float m0 = fmaxf(fmaxf(fmaxf(s[0], s[1]), fmaxf(s[2], s[3])),
                     fmaxf(fmaxf(s[4], s[5]), fmaxf(s[6], s[7])));
    float m1 = fmaxf(fmaxf(fmaxf(s[8], s[9]), fmaxf(s[10], s[11])),
                     fmaxf(fmaxf(s[12], s[13]), fmaxf(s[14], s[15])));
    float pmax = fmaxf(m0, m1);
    pmax = fmaxf(pmax, __shfl_xor(pmax, 16));
    pmax = fmaxf(pmax, __shfl_xor(pmax, 32));
    float sc = 1.0f;
    if (__ballot(pmax > mrun + 8.0f)) {
      float mnew = fmaxf(mrun, pmax);
      sc = exp2f((mrun - mnew) * L2E);
      lsum *= sc;
      mrun = mnew;
    }
    if (g == 0) Slds[buf][w * 16 + m16] = sc;
    const float ml = mrun * L2E;
    float p[16], ps = 0.f;
    #pragma unroll
    for (int j2 = 0; j2 < 16; ++j2) { p[j2] = exp2f(fmaf(s[j2], L2E, -ml)); ps += p[j2]; }
    lsum += ps;
    {
      const int qi = w * 16 + m16;
      char* pb = (char*)Plds + buf * 8192 + qi * 128;
      const uint32_t Mr = (uint32_t)((qi & 7) << 4);
      #pragma unroll
      for (int j = 0; j < 4; ++j) {
        uint2 val;
        val.x = (uint32_t)f2bf(p[j*4+0]) | ((uint32_t)f2bf(p[j*4+1]) << 16);
        val.y = (uint32_t)f2bf(p[j*4+2]) | ((uint32_t)f2bf(p[j*4+3]) << 16);
        *(uint2*)(pb + ((uint32_t)(j * 32 + g * 8) ^ Mr)) = val;
      }
    }
    __syncthreads();
    f32x4 scv[4];
    #pragma unroll
    for (int t = 0; t < 4; ++t) scv[t] = *(const f32x4*)&Slds[buf][t * 16 + g * 4];
    int needmul = 0;
    #pragma unroll
    for (int t = 0; t < 4; ++t)
      #pragma unroll
      for (int r = 0; r < 4; ++r) needmul |= (scv[t][r] != 1.0f);
    if (__ballot(needmul)) {
      #pragma unroll
      for (int t = 0; t < 4; ++t)
        #pragma unroll
        for (int ct = 0; ct < 2; ++ct)
          #pragma unroll
          for (int r = 0; r < 4; ++r) acc[t][ct][r] *= scv[t][r];
    }
    const char* pbr = (const char*)Plds + buf * 8192;
    const uint32_t Mr2 = (uint32_t)((m16 & 7) << 4);
    #pragma unroll
    for (int t = 0; t < 4; ++t) {
      #pragma unroll
      for (int h = 0; h < 2; ++h) {
        short8v pa = *(const short8v*)(pbr + (t * 16 + m16) * 128
                                       + ((uint32_t)(h * 64 + g * 16) ^ Mr2));
        #pragma unroll
        for (int ct = 0; ct < 2; ++ct)
          acc[t][ct] = __builtin_amdgcn_mfma_f32_16x16x32_bf16(pa, vf[ct][h], acc[t][ct], 0, 0, 0);
      }
    }
  };

  #pragma unroll 1
  for (int kt = kt0; kt < kt0 + 32; kt += 2) {
    body(kt, kfA, kfB);
    body(kt + 1, kfB, kfA);
  }

  if (ch == 0 && g == 0) {
    const size_t mi = (size_t)kjh * 16384 + bN + q0 + w * 16 + m16;
    M[mi] = mrun;
    L[mi] = lsum;
  }
  if (kjh == 0) {
    #pragma unroll
    for (int t = 0; t < 4; ++t)
      #pragma unroll
      for (int ct = 0; ct < 2; ++ct) {
        const int c = cb + ct * 16 + m16;
        const int qi = q0 + t * 16 + g * 4;
        *(f32x4*)(O0 + ((size_t)(b * 256 + c)) * 4096 + qi) = acc[t][ct];
      }
  } else {
    #pragma unroll
    for (int t = 0; t < 4; ++t)
      #pragma unroll
      for (int ct = 0; ct < 2; ++ct) {
        const int c = cb + ct * 16 + m16;
        const int qi = q0 + t * 16 + g * 4;
        uint2 pk;
        pk.x = (uint32_t)f2bf(acc[t][ct][0]) | ((uint32_t)f2bf(acc[t][ct][1]) << 16);
        pk.y = (uint32_t)f2bf(acc[t][ct][2]) | ((uint32_t)f2bf(acc[t][ct][3]) << 16);
        *(uint2*)(O1 + ((size_t)(b * 256 + c)) * 4096 + qi) = pk;
      }
  }
}

// ---------------- LSE-combine + residual (streaming, no reductions) ----------------
// grid 1024: b = bid>>8; r = bid&255 -> 64-qi tile (r>>2), 64-c quarter (r&3).
// Thread: 8 c-rows x 2 qi. O0 aliases out; each element read-then-written by
// the same thread.
__global__ __launch_bounds__(256) void combine_kernel(
    const float* O0, const ushort* __restrict__ O1,
    const float* __restrict__ M, const float* __restrict__ L,
    const float* __restrict__ x, const float* __restrict__ gamma,
    float* out)
{
  const int t = threadIdx.x;
  const int bid = blockIdx.x;
  const int b = bid >> 8, r = bid & 255;
  const int qi = (r >> 2) * 64 + (t & 31) * 2;
  const int c0 = (r & 3) * 64 + (t >> 5) * 8;
  const size_t idxq = (size_t)b * 4096 + qi;
  const float L2E = 1.44269504f;

  float2 m0 = *(const float2*)(M + idxq);
  float2 m1 = *(const float2*)(M + 16384 + idxq);
  float2 l0 = *(const float2*)(L + idxq);
  float2 l1 = *(const float2*)(L + 16384 + idxq);
  float mxx = fmaxf(m0.x, m1.x), mxy = fmaxf(m0.y, m1.y);
  float a0x = exp2f((m0.x - mxx) * L2E), a1x = exp2f((m1.x - mxx) * L2E);
  float a0y = exp2f((m0.y - mxy) * L2E), a1y = exp2f((m1.y - mxy) * L2E);
  float invx = 1.0f / (l0.x * a0x + l1.x * a1x);
  float invy = 1.0f / (l0.y * a0y + l1.y * a1y);
  a0x *= invx; a1x *= invx; a0y *= invy; a1y *= invy;
  const float gm = gamma[0];

  #pragma unroll
  for (int cc = 0; cc < 8; ++cc) {
    const size_t row = ((size_t)(b * 256 + c0 + cc)) * 4096 + qi;
    float2 o0 = *(const float2*)(O0 + row);
    ushort2 o1 = *(const ushort2*)(O1 + row);
    float2 xv = *(const float2*)(x + row);
    float2 ov;
    ov.x = fmaf(gm, a0x * o0.x + a1x * bf2f(o1.x), xv.x);
    ov.y = fmaf(gm, a0y * o0.y + a1y * bf2f(o1.y), xv.y);
    *(float2*)(out + row) = ov;
  }
}

// ---------------- ECA gate: full row reduce + gate + scale ----------------
// grid 1024 (b = bid>>8, c = bid&255), block 256. Row loaded once into regs,
// block-reduced, gated, scaled, stored.
__global__ __launch_bounds__(256) void eca_kernel(
    const float* __restrict__ weca, float* __restrict__ out)
{
  __shared__ float red[4];
  const int t = threadIdx.x;
  const int lane = t & 63;
  const int w = __builtin_amdgcn_readfirstlane(t >> 6);
  const int b = blockIdx.x >> 8, c = blockIdx.x & 255;
  float4* row = (float4*)(out + ((size_t)(b * 256 + c)) * 4096);

  float4 v[4];
  float s = 0.f;
  #pragma unroll
  for (int i = 0; i < 4; ++i) {
    v[i] = row[t + i * 256];
    s += (v[i].x + v[i].y) + (v[i].z + v[i].w);
  }
  #pragma unroll
  for (int o = 32; o >= 1; o >>= 1) s += __shfl_xor(s, o);
  if (lane == 0) red[w] = s;
  __syncthreads();
  const float tot = (red[0] + red[1]) + (red[2] + red[3]);
  const float gate = 1.0f / (1.0f + expf(-weca[c * 3 + 1] * tot * (1.0f / 4096.0f)));
  #pragma unroll
  for (int i = 0; i < 4; ++i) {
    v[i].x *= gate; v[i].y *= gate; v[i].z *= gate; v[i].w *= gate;
    row[t + i * 256] = v[i];
  }
}

extern "C" void kernel_launch(void* const* d_in, const int* in_sizes, int n_in,
                              void* d_out, int out_size, void* d_ws, size_t ws_size,
                              hipStream_t stream) {
  const float* x     = (const float*)d_in[0];
  const float* Wq    = (const float*)d_in[1];
  const float* bq    = (const float*)d_in[2];
  const float* Wk    = (const float*)d_in[3];
  const float* bk    = (const float*)d_in[4];
  const float* Wv    = (const float*)d_in[5];
  const float* bv    = (const float*)d_in[6];
  const float* gamma = (const float*)d_in[7];
  const float* weca  = (const float*)d_in[8];
  float* out = (float*)d_out;

  char* ws = (char*)d_ws;
  ushort* WS = (ushort*)(ws);                    // 160 KB [320][256] bf16
  float*  BS = (float*)(ws + 0x28000);           // 1.3 KB [320] fp32
  ushort* qT = (ushort*)(ws + 0x30000);          // 1 MB  [B][N][32] bf16
  ushort* kT = (ushort*)(ws + 0x130000);         // 1 MB  [B][N][32] bf16
  ushort* vO = (ushort*)(ws + 0x230000);         // 8 MB  [B][256][N] bf16
  ushort* O1 = (ushort*)(ws + 0xA30000);         // 8 MB  [B][256][N] bf16 (kj-half 1)
  float*  M  = (float*)(ws + 0x1230000);         // 128 KB [2][B][N]
  float*  L  = (float*)(ws + 0x1250000);         // 128 KB [2][B][N]

  pack_w_kernel<<<dim3(320), 64, 0, stream>>>(Wq, bq, Wk, bk, Wv, bv, WS, BS);
  proj_gemm_kernel<<<dim3(128, 4), 256, 0, stream>>>(x, WS, BS, qT, kT, vO);
  attn_kernel<<<dim3(1024), 256, 0, stream>>>(qT, kT, vO, out, O1, M, L);
  combine_kernel<<<dim3(1024), 256, 0, stream>>>(out, O1, M, L, x, gamma, out);
  eca_kernel<<<dim3(1024), 256, 0, stream>>>(weca, out);
}